// Round 8
// baseline (6192.893 us; speedup 1.0000x reference)
//
#include <hip/hip_runtime.h>
#include <stdint.h>

constexpr int kS = 512;   // sequence length
constexpr int kB = 32;    // batch (only element 0 decoded)
constexpr int kH = 512;   // hidden
constexpr int kV = 64;    // tags

// ---------------------------------------------------------------------------
// ws layout (floats):
//   X    [512][512]     @ 0        (262144)
//   H0L  [2][512][512]  @ 262144   (524288)  local-TCC handoff copy
//   H0G  [2][512][512]  @ 786432   (524288)  MALL copy (fallback + downstream)
//   H1L  [2][512][512]  @ 1310720  (524288)
//   H1G  [2][512][512]  @ 1835008  (524288)
//   LOG  [512][64]      @ 2359296  (32768)
//   FL0  [2][512][32] u @ 2392064  (32768)   per-(dir,t,wg) ready flags, L0
//   FL1  [2][512][32] u @ 2424832  (32768)   ... layer 1
//   CLM  [16] int       @ 2457600  per-XCD claim counters (2 kernels x 8)
// H*L/H*G memset 0xFF (sentinel NaN, unreachable for |h|<1); FL/CLM memset 0.
// ---------------------------------------------------------------------------

__device__ __forceinline__ float fast_sigmoid(float x) {
  return __builtin_amdgcn_rcpf(1.0f + __expf(-x));
}
__device__ __forceinline__ float fast_tanh(float x) {
  return 1.0f - 2.0f * __builtin_amdgcn_rcpf(1.0f + __expf(2.0f * x));
}
__device__ __forceinline__ float bcast(float v, int k) {
  return __uint_as_float(__builtin_amdgcn_readlane(__float_as_uint(v), k));
}
// MALL-coherent poll load (sc0 sc1 = device coherence point) -- the proven
// r3/r7 channel.
__device__ __forceinline__ unsigned ld_mall_nowait(const unsigned* p) {
  unsigned r;
  asm volatile("global_load_dword %0, %1, off sc0 sc1" : "=v"(r) : "v"(p));
  return r;
}
__device__ __forceinline__ void wait_vm0(unsigned& r) {
  asm volatile("s_waitcnt vmcnt(0)" : "+v"(r)::"memory");
}
__device__ __forceinline__ unsigned ld_mall(const unsigned* p) {
  unsigned r;
  asm volatile("global_load_dword %0, %1, off sc0 sc1\n\ts_waitcnt vmcnt(0)"
               : "=v"(r) : "v"(p) : "memory");
  return r;
}
// Local-XCD channel. Atomic RMW executes AT the TCC (XCD L2) when sc1 is
// absent -- unlike r6's plain sc0 ld/st (falsified), the TCC is a guaranteed
// serialization point for atomics. sc0 on an atomic = return old value.
__device__ __forceinline__ unsigned ld_l2(const unsigned* p) {
  unsigned r;
  asm volatile("global_load_dword %0, %1, off sc0\n\ts_waitcnt vmcnt(0)"
               : "=v"(r) : "v"(p) : "memory");
  return r;
}
__device__ __forceinline__ void atomic_pub_local(unsigned* p, unsigned v) {
  asm volatile("global_atomic_swap %0, %1, off" :: "v"(p), "v"(v) : "memory");
}
__device__ __forceinline__ unsigned atomic_probe_local(const unsigned* p) {
  unsigned r, z = 0;
  asm volatile("global_atomic_or %0, %1, %2, off sc0\n\ts_waitcnt vmcnt(0)"
               : "=v"(r) : "v"(p), "v"(z) : "memory");
  return r;
}

__global__ __launch_bounds__(128) void k_embed(const int* __restrict__ src,
                                               const float* __restrict__ emb,
                                               float* __restrict__ X) {
  const int t = blockIdx.x;
  const int s = src[t * kB];  // batch 0 token
  const float4* e = (const float4*)(emb + (size_t)s * 512);
  float4* x = (float4*)(X + (size_t)t * 512);
  x[threadIdx.x] = e[threadIdx.x];
}

// Fused recurrence. 256 blocks, claim-based placement (r6 infra, verified):
// blocks read HW_REG_XCC_ID, XCD0 ranks 0..31 -> dir0, XCD1 -> dir1, rest
// exit. Handoff has TWO channels, mode MEASURED per wave at s==1 (sticky):
//  - local: producer 16x global_atomic_swap (local TCC) -> vmcnt drain ->
//    flag swap; consumer probes 4 flags (atomic_or sc0, same TCC) then
//    coalesced sc0 bulk read. Expected lambda ~200-400cyc.
//  - mall: exact r7 path (pre-issued sc1 poll + chunked h-matvec).
// Producer always dual-publishes HG (agent/MALL) -> fallback & downstream
// kernels are always correct; a dead local channel costs ~0 vs r7.
template <int KZ>
__global__ __launch_bounds__(512, 1) void k_rec(
    const float* __restrict__ Z0,   // layer0: X; layer1: H0G fwd
    const float* __restrict__ Z1,   // layer1: H0G bwd (unused for KZ==512)
    const float* __restrict__ Wih,  // [2][2048][KZ]
    const float* __restrict__ Whh,  // [2][2048][512]
    const float* __restrict__ bih,  // [2][2048]
    const float* __restrict__ bhh,  // [2][2048]
    float* __restrict__ HL,         // [2][512][512] local-TCC copy
    float* __restrict__ HG,         // [2][512][512] MALL copy
    unsigned* __restrict__ FL,      // [2][512][32] flags (zeroed)
    int* __restrict__ claims) {     // [8] per-XCD claim counters (zeroed)
  constexpr int ZPW = KZ / 8;       // z k-slice per wave (64 or 128)
  __shared__ float part[64 * 9];    // [row][wave], stride 9 (odd): conflict-ok
  __shared__ int claim_s;
  const int tid = threadIdx.x;

  if (tid == 0) {
    unsigned x;
    asm volatile("s_getreg_b32 %0, hwreg(HW_REG_XCC_ID)" : "=s"(x));
    x &= 7u;
    const int r = atomicAdd(claims + x, 1);  // device-scope
    claim_s = (x < 2u && r < 32) ? (int)((x << 5) | r) : -1;
  }
  __syncthreads();
  const int cl = claim_s;
  if (cl < 0) return;  // 224 idle blocks exit
  const int dir = cl >> 5, wg = cl & 31;

  const int wv = tid >> 6, l = tid & 63;
  const float* WihB = Wih + (size_t)dir * 2048 * KZ;
  const float* WhhB = Whh + (size_t)dir * 2048 * 512;
  float* HbL = HL + (size_t)dir * kS * kH;
  float* HbG = HG + (size_t)dir * kS * kH;
  unsigned* FLb = FL + (size_t)dir * kS * 32;
  const int grow = (l >> 4) * 512 + wg * 16 + (l & 15);

  // --- one-time weight loads into registers ---
  float ww[64];
  {
    const float* wp = WhhB + (size_t)grow * 512 + wv * 64;
#pragma unroll
    for (int i = 0; i < 64; i += 4) {
      const float4 v = *(const float4*)(wp + i);
      ww[i] = v.x; ww[i + 1] = v.y; ww[i + 2] = v.z; ww[i + 3] = v.w;
    }
  }
  float zw[ZPW];
  {
    const float* zp = WihB + (size_t)grow * KZ + wv * ZPW;
#pragma unroll
    for (int i = 0; i < ZPW; i += 4) {
      const float4 v = *(const float4*)(zp + i);
      zw[i] = v.x; zw[i + 1] = v.y; zw[i + 2] = v.z; zw[i + 3] = v.w;
    }
  }
  float bias = 0.0f;
  if (wv == 0) bias = bih[dir * 2048 + grow] + bhh[dir * 2048 + grow];
  float cstate = 0.0f;  // live in wave 0, lanes < 16

  const float* zbase = (KZ == 512) ? Z0 : ((wv < 4) ? Z0 : Z1);
  const int zoff = (KZ == 512) ? tid : ((wv & 3) * 128 + l);

  const int t0 = dir ? (kS - 1) : 0;
  float zc0 = zbase[(size_t)t0 * 512 + zoff];
  float zc1 = (KZ == 1024) ? zbase[(size_t)t0 * 512 + zoff + 64] : 0.0f;

  int lmode = -1;  // -1 undecided, 0 MALL, 1 local-TCC (per-wave sticky)

  for (int s = 0; s < kS; s++) {
    const int t = dir ? (kS - 1 - s) : s;
    int tn = dir ? (t - 1) : (t + 1);
    if (tn < 0) tn = 0;
    if (tn > kS - 1) tn = kS - 1;
    int tp = dir ? (t + 1) : (t - 1);
    if (tp < 0) tp = 0;
    if (tp > kS - 1) tp = kS - 1;
    const unsigned* gp = (const unsigned*)(HbG + (size_t)tp * kH) + tid;
    const unsigned* lp = (const unsigned*)(HbL + (size_t)tp * kH) + tid;
    const unsigned* flp = FLb + (size_t)tp * 32 + 4 * wv;

    // --- MALL poll pre-issue (mall/undecided modes): RTT hides under z ---
    unsigned u = 0;
    if (s > 0 && lmode != 1) u = ld_mall_nowait(gp);

    // next-step z prefetch (independent, compiler-tracked waitcnt)
    const float zn0 = zbase[(size_t)tn * 512 + zoff];
    const float zn1 = (KZ == 1024) ? zbase[(size_t)tn * 512 + zoff + 64] : 0.0f;

    // --- input-gate matvec: independent of h ---
    float a0 = 0.f, a1 = 0.f, a2 = 0.f, a3 = 0.f;
#pragma unroll
    for (int k = 0; k < 64; k += 4) {
      a0 += zw[k + 0] * bcast(zc0, k + 0);
      a1 += zw[k + 1] * bcast(zc0, k + 1);
      a2 += zw[k + 2] * bcast(zc0, k + 2);
      a3 += zw[k + 3] * bcast(zc0, k + 3);
    }
    if (KZ == 1024) {
#pragma unroll
      for (int k = 0; k < 64; k += 4) {
        a0 += zw[64 + k + 0] * bcast(zc1, k + 0);
        a1 += zw[64 + k + 1] * bcast(zc1, k + 1);
        a2 += zw[64 + k + 2] * bcast(zc1, k + 2);
        a3 += zw[64 + k + 3] * bcast(zc1, k + 3);
      }
    }

    if (s > 0) {
      if (lmode == 1) {
        // --- local-TCC path: probe 4 flags, then coalesced sc0 bulk read ---
        unsigned fs = 0;
        while (true) {
          if (l < 4 && fs == 0) fs = atomic_probe_local(flp + l);
          if ((__ballot(fs != 0) & 0xFull) == 0xFull) break;
        }
        u = ld_l2(lp);
        int tries = 0;
        while (__ballot(u == 0xFFFFFFFFu)) {  // belt-and-braces
          if (u == 0xFFFFFFFFu) {
            tries++;
            u = (tries <= 8) ? ld_l2(lp) : ld_mall(gp);
          }
        }
        const float hq = __uint_as_float(u);
#pragma unroll
        for (int k = 0; k < 64; k += 4) {
          a0 += ww[k + 0] * bcast(hq, k + 0);
          a1 += ww[k + 1] * bcast(hq, k + 1);
          a2 += ww[k + 2] * bcast(hq, k + 2);
          a3 += ww[k + 3] * bcast(hq, k + 3);
        }
      } else if (lmode == 0) {
        // --- r7 MALL path: chunked h-matvec behind sub-ballots ---
        wait_vm0(u);
#pragma unroll
        for (int q = 0; q < 4; q++) {
          const unsigned long long cm = 0xFFFFULL << (q * 16);
          while (__ballot(u == 0xFFFFFFFFu) & cm) {
            if (u == 0xFFFFFFFFu) u = ld_mall(gp);
          }
          const float hq = __uint_as_float(u);
#pragma unroll
          for (int k = q * 16; k < q * 16 + 16; k += 4) {
            a0 += ww[k + 0] * bcast(hq, k + 0);
            a1 += ww[k + 1] * bcast(hq, k + 1);
            a2 += ww[k + 2] * bcast(hq, k + 2);
            a3 += ww[k + 3] * bcast(hq, k + 3);
          }
        }
      } else {
        // --- s==1 diagnosis: race local flags vs MALL, pick sticky mode ---
        wait_vm0(u);
        unsigned fs = 0;
        bool local_ok = false;
        while (true) {
          if (l < 4 && fs == 0) fs = atomic_probe_local(flp + l);
          if ((__ballot(fs != 0) & 0xFull) == 0xFull) { local_ok = true; break; }
          if (__ballot(u == 0xFFFFFFFFu) == 0) break;  // MALL won the race
          if (u == 0xFFFFFFFFu) u = ld_mall(gp);
        }
        if (local_ok) {
          lmode = 1;
          u = ld_l2(lp);
          int tries = 0;
          while (__ballot(u == 0xFFFFFFFFu)) {
            if (u == 0xFFFFFFFFu) {
              tries++;
              u = (tries <= 8) ? ld_l2(lp) : ld_mall(gp);
            }
          }
        } else {
          lmode = 0;
        }
        const float hq = __uint_as_float(u);
#pragma unroll
        for (int k = 0; k < 64; k += 4) {
          a0 += ww[k + 0] * bcast(hq, k + 0);
          a1 += ww[k + 1] * bcast(hq, k + 1);
          a2 += ww[k + 2] * bcast(hq, k + 2);
          a3 += ww[k + 3] * bcast(hq, k + 3);
        }
      }
    }
    part[l * 9 + wv] = (a0 + a1) + (a2 + a3);
    __syncthreads();
    // waves 1..7 fall through to next step immediately; wave 0 does the cell.
    if (wv == 0) {
      float ssum = bias;
#pragma unroll
      for (int w = 0; w < 8; w++) ssum += part[l * 9 + w];
      // rows: i[0,16) f[16,32) g[32,48) o[48,64): one transcendental per lane
      const float act = (l >= 32 && l < 48) ? fast_tanh(ssum)
                                            : fast_sigmoid(ssum);
      const float fg = __shfl(act, (l + 16) & 63);
      const float gt = __shfl(act, (l + 32) & 63);
      const float og = __shfl(act, (l + 48) & 63);
      unsigned hv = 0;
      if (l < 16) {
        cstate = fg * cstate + act * gt;  // act == sigmoid(i) here
        const float h = og * fast_tanh(cstate);
        hv = __float_as_uint(h);
        atomic_pub_local((unsigned*)(HbL + (size_t)t * kH) + wg * 16 + l, hv);
      }
      // drain the 16 data swaps at the TCC, then raise the flag
      asm volatile("s_waitcnt vmcnt(0)" ::: "memory");
      if (l == 0) atomic_pub_local(FLb + (size_t)t * 32 + wg, 1u);
      if (l < 16) {  // MALL copy: fallback + downstream kernels
        __hip_atomic_store((unsigned*)(HbG + (size_t)t * kH) + wg * 16 + l,
                           hv, __ATOMIC_RELAXED, __HIP_MEMORY_SCOPE_AGENT);
      }
    }
    zc0 = zn0;
    zc1 = zn1;
  }
}

__global__ __launch_bounds__(256) void k_logits(const float* __restrict__ H1,
                                                const float* __restrict__ Wout,
                                                const float* __restrict__ bout,
                                                float* __restrict__ LOG) {
  __shared__ float hl[1024];
  const int t = blockIdx.x;
  const int tid = threadIdx.x;
  float4* hl4 = (float4*)hl;
  if (tid < 128)
    hl4[tid] = ((const float4*)(H1 + (size_t)t * kH))[tid];
  else
    hl4[tid] = ((const float4*)(H1 + (size_t)(kS + t) * kH))[tid - 128];
  __syncthreads();
  const int v = tid >> 2, q = tid & 3;
  const float4* w4 = (const float4*)(Wout + (size_t)v * 1024);
  float4 a = {0, 0, 0, 0};
#pragma unroll 8
  for (int j = 0; j < 64; j++) {
    const int idx = j * 4 + q;
    const float4 w = w4[idx];
    const float4 x = hl4[idx];
    a.x += w.x * x.x; a.y += w.y * x.y; a.z += w.z * x.z; a.w += w.w * x.w;
  }
  float acc = (a.x + a.y) + (a.z + a.w);
  acc += __shfl_xor(acc, 1);
  acc += __shfl_xor(acc, 2);
  if (q == 0) LOG[(size_t)t * kV + v] = acc + bout[v];
}

// Single-wave Viterbi: lane c holds trans column c (64 VGPRs); per step a
// max-plus matvec via readlane broadcast, 4 independent sub-chains merged
// ascending (strict > everywhere == numpy first-max). No LDS/global loads or
// syncs in the recurrence.
__global__ __launch_bounds__(64) void k_viterbi(const float* __restrict__ LOG,
                                                const float* __restrict__ trans,
                                                int* __restrict__ out) {
  __shared__ unsigned char bp[511 * 64];
  const int c = threadIdx.x;
  float tr[64];
#pragma unroll
  for (int p = 0; p < 64; p++) tr[p] = trans[p * 64 + c];
  float delta = LOG[c];
  for (int t = 1; t < kS; t++) {
    const float lg = LOG[t * 64 + c];  // prefetch early
    float b0 = bcast(delta, 0) + tr[0];
    float b1 = bcast(delta, 16) + tr[16];
    float b2 = bcast(delta, 32) + tr[32];
    float b3 = bcast(delta, 48) + tr[48];
    int i0 = 0, i1 = 16, i2 = 32, i3 = 48;
#pragma unroll
    for (int j = 1; j < 16; j++) {
      { const float sc = bcast(delta, j) + tr[j];
        if (sc > b0) { b0 = sc; i0 = j; } }
      { const float sc = bcast(delta, 16 + j) + tr[16 + j];
        if (sc > b1) { b1 = sc; i1 = 16 + j; } }
      { const float sc = bcast(delta, 32 + j) + tr[32 + j];
        if (sc > b2) { b2 = sc; i2 = 32 + j; } }
      { const float sc = bcast(delta, 48 + j) + tr[48 + j];
        if (sc > b3) { b3 = sc; i3 = 48 + j; } }
    }
    float best = b0; int bi = i0;
    if (b1 > best) { best = b1; bi = i1; }
    if (b2 > best) { best = b2; bi = i2; }
    if (b3 > best) { best = b3; bi = i3; }
    bp[(t - 1) * 64 + c] = (unsigned char)bi;
    delta = best + lg;
  }
  __syncthreads();
  float b = bcast(delta, 0);
  int a = 0;
#pragma unroll
  for (int p = 1; p < 64; p++) {
    const float v = bcast(delta, p);
    if (v > b) { b = v; a = p; }
  }
  if (c == 0) {
    int idx = a;
    out[kS - 1] = idx;
    for (int t = kS - 2; t >= 0; t--) {
      idx = bp[t * 64 + idx];
      out[t] = idx;
    }
  }
}

extern "C" void kernel_launch(void* const* d_in, const int* in_sizes, int n_in,
                              void* d_out, int out_size, void* d_ws,
                              size_t ws_size, hipStream_t stream) {
  (void)in_sizes; (void)n_in; (void)out_size; (void)ws_size;
  const int* source  = (const int*)d_in[0];
  const float* emb   = (const float*)d_in[2];
  const float* Wih0  = (const float*)d_in[3];
  const float* Whh0  = (const float*)d_in[4];
  const float* bih0  = (const float*)d_in[5];
  const float* bhh0  = (const float*)d_in[6];
  const float* Wih1  = (const float*)d_in[7];
  const float* Whh1  = (const float*)d_in[8];
  const float* bih1  = (const float*)d_in[9];
  const float* bhh1  = (const float*)d_in[10];
  const float* Wout  = (const float*)d_in[11];
  const float* bout  = (const float*)d_in[12];
  const float* trans = (const float*)d_in[13];

  float* ws = (float*)d_ws;
  float* X   = ws;
  float* H0L = ws + 262144;
  float* H0G = ws + 786432;
  float* H1L = ws + 1310720;
  float* H1G = ws + 1835008;
  float* LOG = ws + 2359296;
  unsigned* FL0 = (unsigned*)(ws + 2392064);
  unsigned* FL1 = (unsigned*)(ws + 2424832);
  int*      CLM = (int*)(ws + 2457600);

  // sentinel-init handoff buffers (8 MB of 0xFF = NaN, unreachable for
  // computed h); zero flags + claim counters. Every launch (0xAA re-poison).
  hipMemsetAsync(H0L, 0xFF, (size_t)4 * 524288 * sizeof(float), stream);
  hipMemsetAsync(FL0, 0, (size_t)(2 * 32768 + 16) * sizeof(int), stream);

  k_embed<<<kS, 128, 0, stream>>>(source, emb, X);
  k_rec<512><<<256, 512, 0, stream>>>(X, X, Wih0, Whh0, bih0, bhh0,
                                      H0L, H0G, FL0, CLM);
  k_rec<1024><<<256, 512, 0, stream>>>(H0G, H0G + 262144, Wih1, Whh1, bih1,
                                       bhh1, H1L, H1G, FL1, CLM + 8);
  k_logits<<<kS, 256, 0, stream>>>(H1G, Wout, bout, LOG);
  k_viterbi<<<1, 64, 0, stream>>>(LOG, trans, (int*)d_out);
}